// Round 1
// baseline (2932.080 us; speedup 1.0000x reference)
//
#include <hip/hip_runtime.h>
#include <math.h>

#define NEG 0.2f

__device__ __forceinline__ void atomAddF(float* p, float v) {
  __hip_atomic_fetch_add(p, v, __ATOMIC_RELAXED, __HIP_MEMORY_SCOPE_AGENT);
}

__device__ __forceinline__ float eluf(float x) {
  return x > 0.0f ? x : expf(x) - 1.0f;
}

// ---------------- init kernels ----------------
__global__ __launch_bounds__(256) void init_out1(float* __restrict__ out1,
                                                 const float* __restrict__ b1, int total) {
  int q = blockIdx.x * 256 + threadIdx.x;
  if (q < total) out1[q] = b1[q & 63];
}

__global__ __launch_bounds__(256) void init_out2(float* __restrict__ out2,
                                                 const float* __restrict__ b2, int total) {
  int q = blockIdx.x * 256 + threadIdx.x;
  if (q < total) out2[q] = b2[q % 40];
}

// ---------------- layer 1 GEMM: h1[N,64] = x[N,512] @ W1[512,64] ----------------
// block: 256 threads, tile 128 rows x 64 cols, K-chunks of 32.
__global__ __launch_bounds__(256) void gemm1(const float* __restrict__ x,
                                             const float* __restrict__ W,
                                             float* __restrict__ h1, int N) {
  __shared__ float xs[128 * 40];  // 128 rows, stride 40 (pad)
  __shared__ float ws[32 * 68];   // 32 k-rows, stride 68 (pad)
  const int tid = threadIdx.x;
  const int n0 = blockIdx.x * 128;
  const int jg = tid & 15;   // col group: j0 = jg*4
  const int ig = tid >> 4;   // row base: rows ig + 16*i, i=0..7
  const int j0 = jg * 4;

  float acc[8][4];
#pragma unroll
  for (int i = 0; i < 8; ++i)
#pragma unroll
    for (int c = 0; c < 4; ++c) acc[i][c] = 0.0f;

  for (int kc = 0; kc < 512; kc += 32) {
    // stage x tile: 128 rows x 32 floats = 1024 float4
#pragma unroll
    for (int p = 0; p < 4; ++p) {
      int q = tid + p * 256;
      int r = q >> 3, c4 = q & 7;
      int n = n0 + r;
      if (n >= N) n = N - 1;
      float4 v = *(const float4*)&x[(size_t)n * 512 + kc + c4 * 4];
      *(float4*)&xs[r * 40 + c4 * 4] = v;
    }
    // stage W tile: 32 rows x 64 floats = 512 float4
#pragma unroll
    for (int p = 0; p < 2; ++p) {
      int q = tid + p * 256;
      int r = q >> 4, c4 = q & 15;
      float4 v = *(const float4*)&W[(size_t)(kc + r) * 64 + c4 * 4];
      *(float4*)&ws[r * 68 + c4 * 4] = v;
    }
    __syncthreads();

#pragma unroll
    for (int k = 0; k < 32; k += 4) {
      float4 wf[4];
#pragma unroll
      for (int kk = 0; kk < 4; ++kk) wf[kk] = *(const float4*)&ws[(k + kk) * 68 + j0];
#pragma unroll
      for (int i = 0; i < 8; ++i) {
        int r = ig + 16 * i;
        float4 xf = *(const float4*)&xs[r * 40 + k];
        float xv;
        xv = xf.x;
        acc[i][0] += xv * wf[0].x; acc[i][1] += xv * wf[0].y;
        acc[i][2] += xv * wf[0].z; acc[i][3] += xv * wf[0].w;
        xv = xf.y;
        acc[i][0] += xv * wf[1].x; acc[i][1] += xv * wf[1].y;
        acc[i][2] += xv * wf[1].z; acc[i][3] += xv * wf[1].w;
        xv = xf.z;
        acc[i][0] += xv * wf[2].x; acc[i][1] += xv * wf[2].y;
        acc[i][2] += xv * wf[2].z; acc[i][3] += xv * wf[2].w;
        xv = xf.w;
        acc[i][0] += xv * wf[3].x; acc[i][1] += xv * wf[3].y;
        acc[i][2] += xv * wf[3].z; acc[i][3] += xv * wf[3].w;
      }
    }
    __syncthreads();
  }

#pragma unroll
  for (int i = 0; i < 8; ++i) {
    int n = n0 + ig + 16 * i;
    if (n < N) {
      float4 v = make_float4(acc[i][0], acc[i][1], acc[i][2], acc[i][3]);
      *(float4*)&h1[(size_t)n * 64 + j0] = v;
    }
  }
}

// ---------------- attention coefficients layer 1 ----------------
// thread per (node, head): asrc1[n,h] = sum_c h1[n,h,c]*as1[h,c] ; same for adst1
__global__ __launch_bounds__(256) void attn_coef1(const float* __restrict__ h1,
                                                  const float* __restrict__ as1,
                                                  const float* __restrict__ ad1,
                                                  float* __restrict__ asrc1,
                                                  float* __restrict__ adst1, int N) {
  int t = blockIdx.x * 256 + threadIdx.x;
  if (t >= N * 8) return;
  int n = t >> 3, h = t & 7;
  float4 v0 = *(const float4*)&h1[(size_t)n * 64 + h * 8];
  float4 v1 = *(const float4*)&h1[(size_t)n * 64 + h * 8 + 4];
  float4 a0 = *(const float4*)&as1[h * 8];
  float4 a1 = *(const float4*)&as1[h * 8 + 4];
  float4 c0 = *(const float4*)&ad1[h * 8];
  float4 c1 = *(const float4*)&ad1[h * 8 + 4];
  float s = v0.x * a0.x + v0.y * a0.y + v0.z * a0.z + v0.w * a0.w +
            v1.x * a1.x + v1.y * a1.y + v1.z * a1.z + v1.w * a1.w;
  float d = v0.x * c0.x + v0.y * c0.y + v0.z * c0.z + v0.w * c0.w +
            v1.x * c1.x + v1.y * c1.y + v1.z * c1.z + v1.w * c1.w;
  asrc1[t] = s;
  adst1[t] = d;
}

// ---------------- layer1 edge pass 1: z1[d,h] += exp(leaky(asrc[s,h]+adst[d,h])) ----------------
__global__ __launch_bounds__(256) void edge_z1(const int* __restrict__ ei,
                                               const float* __restrict__ asrc,
                                               const float* __restrict__ adst,
                                               float* __restrict__ z, int E, int N) {
  int it = blockIdx.x * 256 + threadIdx.x;
  int total = E + N;
  if (it >= total) return;
  int s, d;
  if (it < E) { s = ei[it]; d = ei[E + it]; } else { s = d = it - E; }
  float4 a0 = *(const float4*)&asrc[(size_t)s * 8];
  float4 a1 = *(const float4*)&asrc[(size_t)s * 8 + 4];
  float4 b0 = *(const float4*)&adst[(size_t)d * 8];
  float4 b1v = *(const float4*)&adst[(size_t)d * 8 + 4];
  float e[8] = {a0.x + b0.x,  a0.y + b0.y,  a0.z + b0.z,  a0.w + b0.w,
                a1.x + b1v.x, a1.y + b1v.y, a1.z + b1v.z, a1.w + b1v.w};
#pragma unroll
  for (int h = 0; h < 8; ++h) {
    float v = e[h];
    v = v > 0.0f ? v : NEG * v;
    atomAddF(&z[(size_t)d * 8 + h], expf(v));
  }
}

// ---------------- layer1 edge pass 2: out1[d,:] += alpha * h1[s,:] (wave per edge) ------------
__global__ __launch_bounds__(256) void edge_agg1(const int* __restrict__ ei,
                                                 const float* __restrict__ asrc,
                                                 const float* __restrict__ adst,
                                                 const float* __restrict__ z,
                                                 const float* __restrict__ h1,
                                                 float* __restrict__ out1, int E, int N) {
  long long gid = (long long)blockIdx.x * 256 + threadIdx.x;
  int lane = threadIdx.x & 63;
  long long item = gid >> 6;
  if (item >= (long long)E + N) return;
  int s, d;
  if (item < E) { s = ei[item]; d = ei[E + item]; } else { s = d = (int)(item - E); }
  int h = lane >> 3;
  float e = asrc[(size_t)s * 8 + h] + adst[(size_t)d * 8 + h];
  e = e > 0.0f ? e : NEG * e;
  float alpha = expf(e) / (z[(size_t)d * 8 + h] + 1e-16f);
  float xv = h1[(size_t)s * 64 + lane];
  atomAddF(&out1[(size_t)d * 64 + lane], alpha * xv);
}

// ---------------- layer2 node kernel: elu, h2 = act @ W2, attention coefficients -------------
// block: 256 threads, 64 nodes. out1 already contains b1 (init) + aggregation.
__global__ __launch_bounds__(256) void node_l2(const float* __restrict__ out1,
                                               const float* __restrict__ W2,
                                               const float* __restrict__ as2,
                                               const float* __restrict__ ad2,
                                               float* __restrict__ h2,
                                               float* __restrict__ asrc2,
                                               float* __restrict__ adst2, int N) {
  __shared__ float act[64 * 68];
  __shared__ float w2[64 * 40];
  __shared__ float h2s[64 * 41];
  const int tid = threadIdx.x;
  const int n0 = blockIdx.x * 64;

  for (int q = tid; q < 64 * 40; q += 256) w2[q] = W2[q];

#pragma unroll
  for (int p = 0; p < 4; ++p) {
    int q = tid + p * 256;
    int r = q >> 4, c4 = q & 15;
    int n = n0 + r;
    if (n >= N) n = N - 1;
    float4 v = *(const float4*)&out1[(size_t)n * 64 + c4 * 4];
    float4 o;
    o.x = eluf(v.x); o.y = eluf(v.y); o.z = eluf(v.z); o.w = eluf(v.w);
    *(float4*)&act[r * 68 + c4 * 4] = o;
  }
  __syncthreads();

  const int nl = tid >> 2;         // local node 0..63
  const int k0 = (tid & 3) * 10;   // k range
  float hv[10];
#pragma unroll
  for (int i = 0; i < 10; ++i) hv[i] = 0.0f;
  for (int j = 0; j < 64; ++j) {
    float a = act[nl * 68 + j];
#pragma unroll
    for (int i = 0; i < 10; ++i) hv[i] += a * w2[j * 40 + k0 + i];
  }
  int n = n0 + nl;
  if (n < N) {
#pragma unroll
    for (int i = 0; i < 10; ++i) h2[(size_t)n * 40 + k0 + i] = hv[i];
  }
#pragma unroll
  for (int i = 0; i < 10; ++i) h2s[nl * 41 + k0 + i] = hv[i];
  __syncthreads();

  if (tid < 64) {
    int nn = n0 + tid;
    float s1 = 0.0f, s2 = 0.0f;
    for (int k = 0; k < 40; ++k) {
      float h = h2s[tid * 41 + k];
      s1 += h * as2[k];
      s2 += h * ad2[k];
    }
    if (nn < N) { asrc2[nn] = s1; adst2[nn] = s2; }
  }
}

// ---------------- layer2 edge pass 1 ----------------
__global__ __launch_bounds__(256) void edge_z2(const int* __restrict__ ei,
                                               const float* __restrict__ asrc,
                                               const float* __restrict__ adst,
                                               float* __restrict__ z, int E, int N) {
  int it = blockIdx.x * 256 + threadIdx.x;
  int total = E + N;
  if (it >= total) return;
  int s, d;
  if (it < E) { s = ei[it]; d = ei[E + it]; } else { s = d = it - E; }
  float v = asrc[s] + adst[d];
  v = v > 0.0f ? v : NEG * v;
  atomAddF(&z[d], expf(v));
}

// ---------------- layer2 edge pass 2: out[d,:] += alpha * h2[s,:] (thread per (edge,k)) -----
__global__ __launch_bounds__(256) void edge_agg2(const int* __restrict__ ei,
                                                 const float* __restrict__ asrc,
                                                 const float* __restrict__ adst,
                                                 const float* __restrict__ z,
                                                 const float* __restrict__ h2,
                                                 float* __restrict__ out, int E, int N) {
  long long gid = (long long)blockIdx.x * 256 + threadIdx.x;
  long long total = (long long)(E + N) * 40;
  if (gid >= total) return;
  int it = (int)(gid / 40);
  int k = (int)(gid - (long long)it * 40);
  int s, d;
  if (it < E) { s = ei[it]; d = ei[E + it]; } else { s = d = it - E; }
  float v = asrc[s] + adst[d];
  v = v > 0.0f ? v : NEG * v;
  float alpha = expf(v) / (z[d] + 1e-16f);
  atomAddF(&out[(size_t)d * 40 + k], alpha * h2[(size_t)s * 40 + k]);
}

extern "C" void kernel_launch(void* const* d_in, const int* in_sizes, int n_in,
                              void* d_out, int out_size, void* d_ws, size_t ws_size,
                              hipStream_t stream) {
  const float* x   = (const float*)d_in[0];
  const int*   ei  = (const int*)d_in[1];
  const float* W1  = (const float*)d_in[2];
  const float* as1 = (const float*)d_in[3];
  const float* ad1 = (const float*)d_in[4];
  const float* b1  = (const float*)d_in[5];
  const float* W2  = (const float*)d_in[6];
  const float* as2 = (const float*)d_in[7];
  const float* ad2 = (const float*)d_in[8];
  const float* b2  = (const float*)d_in[9];
  float* out = (float*)d_out;

  const int N = in_sizes[0] / 512;
  const int E = in_sizes[1] / 2;

  float* ws = (float*)d_ws;
  size_t o = 0;
  float* h1    = ws + o; o += (size_t)N * 64;
  float* asrc1 = ws + o; o += (size_t)N * 8;
  float* adst1 = ws + o; o += (size_t)N * 8;
  float* z1    = ws + o; o += (size_t)N * 8;
  float* out1  = ws + o; o += (size_t)N * 64;
  float* h2    = ws + o; o += (size_t)N * 40;
  float* asrc2 = ws + o; o += (size_t)N;
  float* adst2 = ws + o; o += (size_t)N;
  float* z2    = ws + o; o += (size_t)N;

  hipMemsetAsync(z1, 0, (size_t)N * 8 * sizeof(float), stream);
  hipMemsetAsync(z2, 0, (size_t)N * sizeof(float), stream);
  init_out1<<<(N * 64 + 255) / 256, 256, 0, stream>>>(out1, b1, N * 64);
  init_out2<<<(N * 40 + 255) / 256, 256, 0, stream>>>(out, b2, N * 40);

  gemm1<<<(N + 127) / 128, 256, 0, stream>>>(x, W1, h1, N);
  attn_coef1<<<(N * 8 + 255) / 256, 256, 0, stream>>>(h1, as1, ad1, asrc1, adst1, N);

  const int total1 = E + N;
  edge_z1<<<(total1 + 255) / 256, 256, 0, stream>>>(ei, asrc1, adst1, z1, E, N);
  edge_agg1<<<(int)(((long long)total1 * 64 + 255) / 256), 256, 0, stream>>>(
      ei, asrc1, adst1, z1, h1, out1, E, N);

  node_l2<<<(N + 63) / 64, 256, 0, stream>>>(out1, W2, as2, ad2, h2, asrc2, adst2, N);

  edge_z2<<<(total1 + 255) / 256, 256, 0, stream>>>(ei, asrc2, adst2, z2, E, N);
  edge_agg2<<<(int)(((long long)total1 * 40 + 255) / 256), 256, 0, stream>>>(
      ei, asrc2, adst2, z2, h2, out, E, N);
}

// Round 3
// 879.743 us; speedup vs baseline: 3.3329x; 3.3329x over previous
//
#include <hip/hip_runtime.h>
#include <math.h>

#define NEG 0.2f

__device__ __forceinline__ float lrelu(float v) { return v > 0.0f ? v : NEG * v; }
__device__ __forceinline__ float eluf(float x) { return x > 0.0f ? x : expf(x) - 1.0f; }

// ---------------- layer 1 GEMM: h1[N,64] = x[N,512] @ W1[512,64] ----------------
__global__ __launch_bounds__(256) void gemm1(const float* __restrict__ x,
                                             const float* __restrict__ W,
                                             float* __restrict__ h1, int N) {
  __shared__ float xs[128 * 40];
  __shared__ float ws[32 * 68];
  const int tid = threadIdx.x;
  const int n0 = blockIdx.x * 128;
  const int jg = tid & 15;
  const int ig = tid >> 4;
  const int j0 = jg * 4;

  float acc[8][4];
#pragma unroll
  for (int i = 0; i < 8; ++i)
#pragma unroll
    for (int c = 0; c < 4; ++c) acc[i][c] = 0.0f;

  for (int kc = 0; kc < 512; kc += 32) {
#pragma unroll
    for (int p = 0; p < 4; ++p) {
      int q = tid + p * 256;
      int r = q >> 3, c4 = q & 7;
      int n = n0 + r;
      if (n >= N) n = N - 1;
      float4 v = *(const float4*)&x[(size_t)n * 512 + kc + c4 * 4];
      *(float4*)&xs[r * 40 + c4 * 4] = v;
    }
#pragma unroll
    for (int p = 0; p < 2; ++p) {
      int q = tid + p * 256;
      int r = q >> 4, c4 = q & 15;
      float4 v = *(const float4*)&W[(size_t)(kc + r) * 64 + c4 * 4];
      *(float4*)&ws[r * 68 + c4 * 4] = v;
    }
    __syncthreads();

#pragma unroll
    for (int k = 0; k < 32; k += 4) {
      float4 wf[4];
#pragma unroll
      for (int kk = 0; kk < 4; ++kk) wf[kk] = *(const float4*)&ws[(k + kk) * 68 + j0];
#pragma unroll
      for (int i = 0; i < 8; ++i) {
        int r = ig + 16 * i;
        float4 xf = *(const float4*)&xs[r * 40 + k];
        float xv;
        xv = xf.x;
        acc[i][0] += xv * wf[0].x; acc[i][1] += xv * wf[0].y;
        acc[i][2] += xv * wf[0].z; acc[i][3] += xv * wf[0].w;
        xv = xf.y;
        acc[i][0] += xv * wf[1].x; acc[i][1] += xv * wf[1].y;
        acc[i][2] += xv * wf[1].z; acc[i][3] += xv * wf[1].w;
        xv = xf.z;
        acc[i][0] += xv * wf[2].x; acc[i][1] += xv * wf[2].y;
        acc[i][2] += xv * wf[2].z; acc[i][3] += xv * wf[2].w;
        xv = xf.w;
        acc[i][0] += xv * wf[3].x; acc[i][1] += xv * wf[3].y;
        acc[i][2] += xv * wf[3].z; acc[i][3] += xv * wf[3].w;
      }
    }
    __syncthreads();
  }

#pragma unroll
  for (int i = 0; i < 8; ++i) {
    int n = n0 + ig + 16 * i;
    if (n < N) {
      float4 v = make_float4(acc[i][0], acc[i][1], acc[i][2], acc[i][3]);
      *(float4*)&h1[(size_t)n * 64 + j0] = v;
    }
  }
}

// ---------------- attention coefficients layer 1 ----------------
__global__ __launch_bounds__(256) void attn_coef1(const float* __restrict__ h1,
                                                  const float* __restrict__ as1,
                                                  const float* __restrict__ ad1,
                                                  float* __restrict__ asrc1,
                                                  float* __restrict__ adst1, int N) {
  int t = blockIdx.x * 256 + threadIdx.x;
  if (t >= N * 8) return;
  int n = t >> 3, h = t & 7;
  float4 v0 = *(const float4*)&h1[(size_t)n * 64 + h * 8];
  float4 v1 = *(const float4*)&h1[(size_t)n * 64 + h * 8 + 4];
  float4 a0 = *(const float4*)&as1[h * 8];
  float4 a1 = *(const float4*)&as1[h * 8 + 4];
  float4 c0 = *(const float4*)&ad1[h * 8];
  float4 c1 = *(const float4*)&ad1[h * 8 + 4];
  float s = v0.x * a0.x + v0.y * a0.y + v0.z * a0.z + v0.w * a0.w +
            v1.x * a1.x + v1.y * a1.y + v1.z * a1.z + v1.w * a1.w;
  float d = v0.x * c0.x + v0.y * c0.y + v0.z * c0.z + v0.w * c0.w +
            v1.x * c1.x + v1.y * c1.y + v1.z * c1.z + v1.w * c1.w;
  asrc1[t] = s;
  adst1[t] = d;
}

// ---------------- CSR build ----------------
__global__ __launch_bounds__(256) void k_count(const int* __restrict__ ei,
                                               int* __restrict__ deg, int E) {
  int t = blockIdx.x * 256 + threadIdx.x;
  if (t < E) atomicAdd(&deg[ei[E + t]], 1);
}

__global__ __launch_bounds__(256) void scan1(const int* __restrict__ deg,
                                             int* __restrict__ bsum, int N) {
  __shared__ int s[256];
  int t = threadIdx.x;
  int n = blockIdx.x * 256 + t;
  s[t] = n < N ? deg[n] : 0;
  __syncthreads();
  for (int o = 128; o > 0; o >>= 1) {
    if (t < o) s[t] += s[t + o];
    __syncthreads();
  }
  if (t == 0) bsum[blockIdx.x] = s[0];
}

// exclusive-scan the block sums (single block, handles any nb via chunks of 512)
__global__ __launch_bounds__(512) void scan2(int* __restrict__ bsum, int nb) {
  __shared__ int s[512];
  int t = threadIdx.x;
  int carry = 0;
  for (int base = 0; base < nb; base += 512) {
    int i = base + t;
    int v = i < nb ? bsum[i] : 0;
    s[t] = v;
    __syncthreads();
    for (int o = 1; o < 512; o <<= 1) {
      int add = t >= o ? s[t - o] : 0;
      __syncthreads();
      s[t] += add;
      __syncthreads();
    }
    int incl = s[t];
    int tot = s[511];
    if (i < nb) bsum[i] = carry + incl - v;  // exclusive
    __syncthreads();
    carry += tot;
  }
}

__global__ __launch_bounds__(256) void scan3(const int* __restrict__ deg,
                                             const int* __restrict__ boff,
                                             int* __restrict__ rowstart,
                                             int* __restrict__ cur, int N) {
  __shared__ int s[256];
  int t = threadIdx.x;
  int n = blockIdx.x * 256 + t;
  int v = n < N ? deg[n] : 0;
  s[t] = v;
  __syncthreads();
  for (int o = 1; o < 256; o <<= 1) {
    int add = t >= o ? s[t - o] : 0;
    __syncthreads();
    s[t] += add;
    __syncthreads();
  }
  int excl = s[t] - v + boff[blockIdx.x];
  if (n < N) {
    rowstart[n] = excl;
    cur[n] = excl;
  }
}

__global__ __launch_bounds__(256) void k_scatter(const int* __restrict__ ei,
                                                 int* __restrict__ cur,
                                                 int* __restrict__ csr, int E) {
  int t = blockIdx.x * 256 + threadIdx.x;
  if (t >= E) return;
  int s = ei[t], d = ei[E + t];
  int pos = atomicAdd(&cur[d], 1);
  csr[pos] = s;
}

// ---------------- layer 1 aggregation: wave per dst node, fused softmax ----------------
// act[d,c] = elu( (sum_e p_e * h1[s_e,c]) / (sum_e p_e) + b1[c] ),  p_e = exp(leaky(asrc+adst))
__global__ __launch_bounds__(256) void agg1(const int* __restrict__ rowstart,
                                            const int* __restrict__ deg,
                                            const int* __restrict__ csr,
                                            const float* __restrict__ asrc,
                                            const float* __restrict__ adst,
                                            const float* __restrict__ h1,
                                            const float* __restrict__ b1,
                                            float* __restrict__ act, int N) {
  int wid = (blockIdx.x * 256 + threadIdx.x) >> 6;
  if (wid >= N) return;
  int lane = threadIdx.x & 63;
  int h = lane >> 3;
  int d = wid;
  float ad = adst[(size_t)d * 8 + h];
  int rs = rowstart[d], n = deg[d];
  float acc = 0.0f, zs = 0.0f;
  int i = 0;
  for (; i + 1 < n; i += 2) {
    int s0 = csr[rs + i];
    int s1 = csr[rs + i + 1];
    float a0 = asrc[(size_t)s0 * 8 + h];
    float a1 = asrc[(size_t)s1 * 8 + h];
    float x0 = h1[(size_t)s0 * 64 + lane];
    float x1 = h1[(size_t)s1 * 64 + lane];
    float p0 = expf(lrelu(a0 + ad));
    float p1 = expf(lrelu(a1 + ad));
    acc += p0 * x0 + p1 * x1;
    zs += p0 + p1;
  }
  if (i < n) {
    int s0 = csr[rs + i];
    float p0 = expf(lrelu(asrc[(size_t)s0 * 8 + h] + ad));
    acc += p0 * h1[(size_t)s0 * 64 + lane];
    zs += p0;
  }
  // self loop
  {
    float p = expf(lrelu(asrc[(size_t)d * 8 + h] + ad));
    acc += p * h1[(size_t)d * 64 + lane];
    zs += p;
  }
  act[(size_t)d * 64 + lane] = eluf(acc / (zs + 1e-16f) + b1[lane]);
}

// ---------------- layer2 node kernel: h2 = act @ W2, attention coefficients ----------------
__global__ __launch_bounds__(256) void node_l2(const float* __restrict__ act,
                                               const float* __restrict__ W2,
                                               const float* __restrict__ as2,
                                               const float* __restrict__ ad2,
                                               float* __restrict__ h2,
                                               float* __restrict__ asrc2,
                                               float* __restrict__ adst2, int N) {
  __shared__ float acts[64 * 68];
  __shared__ float w2[64 * 40];
  __shared__ float h2s[64 * 41];
  const int tid = threadIdx.x;
  const int n0 = blockIdx.x * 64;

  for (int q = tid; q < 64 * 40; q += 256) w2[q] = W2[q];

#pragma unroll
  for (int p = 0; p < 4; ++p) {
    int q = tid + p * 256;
    int r = q >> 4, c4 = q & 15;
    int n = n0 + r;
    if (n >= N) n = N - 1;
    float4 v = *(const float4*)&act[(size_t)n * 64 + c4 * 4];
    *(float4*)&acts[r * 68 + c4 * 4] = v;
  }
  __syncthreads();

  const int nl = tid >> 2;
  const int k0 = (tid & 3) * 10;
  float hv[10];
#pragma unroll
  for (int i = 0; i < 10; ++i) hv[i] = 0.0f;
  for (int j = 0; j < 64; ++j) {
    float a = acts[nl * 68 + j];
#pragma unroll
    for (int i = 0; i < 10; ++i) hv[i] += a * w2[j * 40 + k0 + i];
  }
  int n = n0 + nl;
  if (n < N) {
#pragma unroll
    for (int i = 0; i < 10; ++i) h2[(size_t)n * 40 + k0 + i] = hv[i];
  }
#pragma unroll
  for (int i = 0; i < 10; ++i) h2s[nl * 41 + k0 + i] = hv[i];
  __syncthreads();

  if (tid < 64) {
    int nn = n0 + tid;
    float s1 = 0.0f, s2 = 0.0f;
    for (int k = 0; k < 40; ++k) {
      float h = h2s[tid * 41 + k];
      s1 += h * as2[k];
      s2 += h * ad2[k];
    }
    if (nn < N) {
      asrc2[nn] = s1;
      adst2[nn] = s2;
    }
  }
}

// ---------------- layer 2 aggregation: wave per dst node ----------------
__global__ __launch_bounds__(256) void agg2(const int* __restrict__ rowstart,
                                            const int* __restrict__ deg,
                                            const int* __restrict__ csr,
                                            const float* __restrict__ asrc,
                                            const float* __restrict__ adst,
                                            const float* __restrict__ h2,
                                            const float* __restrict__ b2,
                                            float* __restrict__ out, int N) {
  int wid = (blockIdx.x * 256 + threadIdx.x) >> 6;
  if (wid >= N) return;
  int lane = threadIdx.x & 63;
  int d = wid;
  float ad = adst[d];
  int rs = rowstart[d], n = deg[d];
  float acc = 0.0f, zs = 0.0f;
  int i = 0;
  for (; i + 1 < n; i += 2) {
    int s0 = csr[rs + i];
    int s1 = csr[rs + i + 1];
    float a0 = asrc[s0];
    float a1 = asrc[s1];
    float x0 = lane < 40 ? h2[(size_t)s0 * 40 + lane] : 0.0f;
    float x1 = lane < 40 ? h2[(size_t)s1 * 40 + lane] : 0.0f;
    float p0 = expf(lrelu(a0 + ad));
    float p1 = expf(lrelu(a1 + ad));
    acc += p0 * x0 + p1 * x1;
    zs += p0 + p1;
  }
  if (i < n) {
    int s0 = csr[rs + i];
    float p0 = expf(lrelu(asrc[s0] + ad));
    float x0 = lane < 40 ? h2[(size_t)s0 * 40 + lane] : 0.0f;
    acc += p0 * x0;
    zs += p0;
  }
  {
    float p = expf(lrelu(asrc[d] + ad));
    float x = lane < 40 ? h2[(size_t)d * 40 + lane] : 0.0f;
    acc += p * x;
    zs += p;
  }
  if (lane < 40) out[(size_t)d * 40 + lane] = acc / (zs + 1e-16f) + b2[lane];
}

extern "C" void kernel_launch(void* const* d_in, const int* in_sizes, int n_in,
                              void* d_out, int out_size, void* d_ws, size_t ws_size,
                              hipStream_t stream) {
  const float* x   = (const float*)d_in[0];
  const int*   ei  = (const int*)d_in[1];
  const float* W1  = (const float*)d_in[2];
  const float* as1 = (const float*)d_in[3];
  const float* ad1 = (const float*)d_in[4];
  const float* b1  = (const float*)d_in[5];
  const float* W2  = (const float*)d_in[6];
  const float* as2 = (const float*)d_in[7];
  const float* ad2 = (const float*)d_in[8];
  const float* b2  = (const float*)d_in[9];
  float* out = (float*)d_out;

  const int N = in_sizes[0] / 512;
  const int E = in_sizes[1] / 2;
  const int NB = (N + 255) / 256;

  float* ws = (float*)d_ws;
  size_t o = 0;
  float* h1    = ws + o; o += (size_t)N * 64;
  float* act   = ws + o; o += (size_t)N * 64;   // elu'd layer-1 output
  float* h2    = ws + o; o += (size_t)N * 40;
  float* asrc1 = ws + o; o += (size_t)N * 8;
  float* adst1 = ws + o; o += (size_t)N * 8;
  float* asrc2 = ws + o; o += (size_t)N;
  float* adst2 = ws + o; o += (size_t)N;
  int* deg      = (int*)(ws + o); o += (size_t)N;
  int* rowstart = (int*)(ws + o); o += (size_t)N;
  int* cur      = (int*)(ws + o); o += (size_t)N;
  int* bsum     = (int*)(ws + o); o += (size_t)NB + 16;
  int* csr      = (int*)(ws + o); o += (size_t)E;

  hipMemsetAsync(deg, 0, (size_t)N * sizeof(int), stream);

  // GEMM + attention coefficients (independent of CSR build)
  gemm1<<<(N + 127) / 128, 256, 0, stream>>>(x, W1, h1, N);
  attn_coef1<<<(N * 8 + 255) / 256, 256, 0, stream>>>(h1, as1, ad1, asrc1, adst1, N);

  // CSR build (dst-sorted), reused by both layers
  k_count<<<(E + 255) / 256, 256, 0, stream>>>(ei, deg, E);
  scan1<<<NB, 256, 0, stream>>>(deg, bsum, N);
  scan2<<<1, 512, 0, stream>>>(bsum, NB);
  scan3<<<NB, 256, 0, stream>>>(deg, bsum, rowstart, cur, N);
  k_scatter<<<(E + 255) / 256, 256, 0, stream>>>(ei, cur, csr, E);

  // layer 1 aggregation (fused softmax-denominator, bias, ELU)
  agg1<<<(N * 64 + 255) / 256, 256, 0, stream>>>(rowstart, deg, csr, asrc1, adst1, h1, b1,
                                                 act, N);

  // layer 2 dense part
  node_l2<<<(N + 63) / 64, 256, 0, stream>>>(act, W2, as2, ad2, h2, asrc2, adst2, N);

  // layer 2 aggregation
  agg2<<<(N * 64 + 255) / 256, 256, 0, stream>>>(rowstart, deg, csr, asrc2, adst2, h2, b2,
                                                 out, N);
}

// Round 4
// 619.322 us; speedup vs baseline: 4.7343x; 1.4205x over previous
//
#include <hip/hip_runtime.h>
#include <math.h>

#define NEG 0.2f

__device__ __forceinline__ float lrelu(float v) { return v > 0.0f ? v : NEG * v; }
__device__ __forceinline__ float eluf(float x) { return x > 0.0f ? x : expf(x) - 1.0f; }

// ---------------- K1: heterogeneous gemm1 (blocks [0,NBg)) + count+rank (rest) ----------------
// gemm: h1[N,64] = x[N,512] @ W1[512,64]
// count: rank[e] = atomicAdd(&deg[dst[e]], 1)   (rank-in-count trick)
__global__ __launch_bounds__(256) void k_gemm_count(const float* __restrict__ x,
                                                    const float* __restrict__ W,
                                                    float* __restrict__ h1,
                                                    const int* __restrict__ ei,
                                                    int* __restrict__ deg,
                                                    int* __restrict__ rankv,
                                                    int N, int E, int NBg) {
  __shared__ float xs[128 * 40];
  __shared__ float ws[32 * 68];

  if ((int)blockIdx.x >= NBg) {
    // -------- count branch: 4 edges per thread --------
    int t0 = (((int)blockIdx.x - NBg) * 256 + (int)threadIdx.x) * 4;
    if (t0 + 3 < E && (E & 3) == 0) {
      int4 d4 = *(const int4*)&ei[E + t0];
      int4 r4;
      r4.x = atomicAdd(&deg[d4.x], 1);
      r4.y = atomicAdd(&deg[d4.y], 1);
      r4.z = atomicAdd(&deg[d4.z], 1);
      r4.w = atomicAdd(&deg[d4.w], 1);
      *(int4*)&rankv[t0] = r4;
    } else {
#pragma unroll
      for (int u = 0; u < 4; ++u) {
        int t = t0 + u;
        if (t < E) rankv[t] = atomicAdd(&deg[ei[E + t]], 1);
      }
    }
    return;
  }

  // -------- gemm branch --------
  const int tid = threadIdx.x;
  const int n0 = blockIdx.x * 128;
  const int jg = tid & 15;
  const int ig = tid >> 4;
  const int j0 = jg * 4;

  float acc[8][4];
#pragma unroll
  for (int i = 0; i < 8; ++i)
#pragma unroll
    for (int c = 0; c < 4; ++c) acc[i][c] = 0.0f;

  for (int kc = 0; kc < 512; kc += 32) {
#pragma unroll
    for (int p = 0; p < 4; ++p) {
      int q = tid + p * 256;
      int r = q >> 3, c4 = q & 7;
      int n = n0 + r;
      if (n >= N) n = N - 1;
      float4 v = *(const float4*)&x[(size_t)n * 512 + kc + c4 * 4];
      *(float4*)&xs[r * 40 + c4 * 4] = v;
    }
#pragma unroll
    for (int p = 0; p < 2; ++p) {
      int q = tid + p * 256;
      int r = q >> 4, c4 = q & 15;
      float4 v = *(const float4*)&W[(size_t)(kc + r) * 64 + c4 * 4];
      *(float4*)&ws[r * 68 + c4 * 4] = v;
    }
    __syncthreads();

#pragma unroll
    for (int k = 0; k < 32; k += 4) {
      float4 wf[4];
#pragma unroll
      for (int kk = 0; kk < 4; ++kk) wf[kk] = *(const float4*)&ws[(k + kk) * 68 + j0];
#pragma unroll
      for (int i = 0; i < 8; ++i) {
        int r = ig + 16 * i;
        float4 xf = *(const float4*)&xs[r * 40 + k];
        float xv;
        xv = xf.x;
        acc[i][0] += xv * wf[0].x; acc[i][1] += xv * wf[0].y;
        acc[i][2] += xv * wf[0].z; acc[i][3] += xv * wf[0].w;
        xv = xf.y;
        acc[i][0] += xv * wf[1].x; acc[i][1] += xv * wf[1].y;
        acc[i][2] += xv * wf[1].z; acc[i][3] += xv * wf[1].w;
        xv = xf.z;
        acc[i][0] += xv * wf[2].x; acc[i][1] += xv * wf[2].y;
        acc[i][2] += xv * wf[2].z; acc[i][3] += xv * wf[2].w;
        xv = xf.w;
        acc[i][0] += xv * wf[3].x; acc[i][1] += xv * wf[3].y;
        acc[i][2] += xv * wf[3].z; acc[i][3] += xv * wf[3].w;
      }
    }
    __syncthreads();
  }

#pragma unroll
  for (int i = 0; i < 8; ++i) {
    int n = n0 + ig + 16 * i;
    if (n < N) {
      float4 v = make_float4(acc[i][0], acc[i][1], acc[i][2], acc[i][3]);
      *(float4*)&h1[(size_t)n * 64 + j0] = v;
    }
  }
}

// ---------------- scans (unchanged) ----------------
__global__ __launch_bounds__(256) void scan1(const int* __restrict__ deg,
                                             int* __restrict__ bsum, int N) {
  __shared__ int s[256];
  int t = threadIdx.x;
  int n = blockIdx.x * 256 + t;
  s[t] = n < N ? deg[n] : 0;
  __syncthreads();
  for (int o = 128; o > 0; o >>= 1) {
    if (t < o) s[t] += s[t + o];
    __syncthreads();
  }
  if (t == 0) bsum[blockIdx.x] = s[0];
}

__global__ __launch_bounds__(512) void scan2(int* __restrict__ bsum, int nb) {
  __shared__ int s[512];
  int t = threadIdx.x;
  int carry = 0;
  for (int base = 0; base < nb; base += 512) {
    int i = base + t;
    int v = i < nb ? bsum[i] : 0;
    s[t] = v;
    __syncthreads();
    for (int o = 1; o < 512; o <<= 1) {
      int add = t >= o ? s[t - o] : 0;
      __syncthreads();
      s[t] += add;
      __syncthreads();
    }
    int incl = s[t];
    int tot = s[511];
    if (i < nb) bsum[i] = carry + incl - v;
    __syncthreads();
    carry += tot;
  }
}

__global__ __launch_bounds__(256) void scan3(const int* __restrict__ deg,
                                             const int* __restrict__ boff,
                                             int* __restrict__ rowstart, int N) {
  __shared__ int s[256];
  int t = threadIdx.x;
  int n = blockIdx.x * 256 + t;
  int v = n < N ? deg[n] : 0;
  s[t] = v;
  __syncthreads();
  for (int o = 1; o < 256; o <<= 1) {
    int add = t >= o ? s[t - o] : 0;
    __syncthreads();
    s[t] += add;
    __syncthreads();
  }
  int excl = s[t] - v + boff[blockIdx.x];
  if (n < N) rowstart[n] = excl;
}

// ---------------- K2: heterogeneous scatter (no atomics) + attn_coef1 ----------------
__global__ __launch_bounds__(256) void k_scatter_attn(const int* __restrict__ ei,
                                                      const int* __restrict__ rankv,
                                                      const int* __restrict__ rowstart,
                                                      int* __restrict__ csr,
                                                      const float* __restrict__ h1,
                                                      const float* __restrict__ as1,
                                                      const float* __restrict__ ad1,
                                                      float* __restrict__ asrc1,
                                                      float* __restrict__ adst1,
                                                      int N, int E, int NBs) {
  if ((int)blockIdx.x < NBs) {
    int t0 = ((int)blockIdx.x * 256 + (int)threadIdx.x) * 4;
    if (t0 + 3 < E && (E & 3) == 0) {
      int4 s4 = *(const int4*)&ei[t0];
      int4 d4 = *(const int4*)&ei[E + t0];
      int4 r4 = *(const int4*)&rankv[t0];
      csr[rowstart[d4.x] + r4.x] = s4.x;
      csr[rowstart[d4.y] + r4.y] = s4.y;
      csr[rowstart[d4.z] + r4.z] = s4.z;
      csr[rowstart[d4.w] + r4.w] = s4.w;
    } else {
#pragma unroll
      for (int u = 0; u < 4; ++u) {
        int t = t0 + u;
        if (t < E) csr[rowstart[ei[E + t]] + rankv[t]] = ei[t];
      }
    }
    return;
  }
  // attn branch
  int t = ((int)blockIdx.x - NBs) * 256 + (int)threadIdx.x;
  if (t >= N * 8) return;
  int n = t >> 3, h = t & 7;
  float4 v0 = *(const float4*)&h1[(size_t)n * 64 + h * 8];
  float4 v1 = *(const float4*)&h1[(size_t)n * 64 + h * 8 + 4];
  float4 a0 = *(const float4*)&as1[h * 8];
  float4 a1 = *(const float4*)&as1[h * 8 + 4];
  float4 c0 = *(const float4*)&ad1[h * 8];
  float4 c1 = *(const float4*)&ad1[h * 8 + 4];
  float s = v0.x * a0.x + v0.y * a0.y + v0.z * a0.z + v0.w * a0.w +
            v1.x * a1.x + v1.y * a1.y + v1.z * a1.z + v1.w * a1.w;
  float d = v0.x * c0.x + v0.y * c0.y + v0.z * c0.z + v0.w * c0.w +
            v1.x * c1.x + v1.y * c1.y + v1.z * c1.z + v1.w * c1.w;
  asrc1[t] = s;
  adst1[t] = d;
}

// ---------------- layer 1 aggregation: wave per dst node, fused softmax+bias+ELU ----------------
__global__ __launch_bounds__(256) void agg1(const int* __restrict__ rowstart,
                                            const int* __restrict__ deg,
                                            const int* __restrict__ csr,
                                            const float* __restrict__ asrc,
                                            const float* __restrict__ adst,
                                            const float* __restrict__ h1,
                                            const float* __restrict__ b1,
                                            float* __restrict__ act, int N) {
  int wid = (blockIdx.x * 256 + threadIdx.x) >> 6;
  if (wid >= N) return;
  int lane = threadIdx.x & 63;
  int h = lane >> 3;
  int d = wid;
  float ad = adst[(size_t)d * 8 + h];
  int rs = rowstart[d], n = deg[d];
  float acc = 0.0f, zs = 0.0f;
  int i = 0;
  for (; i + 3 < n; i += 4) {
    int s0 = csr[rs + i];
    int s1 = csr[rs + i + 1];
    int s2 = csr[rs + i + 2];
    int s3 = csr[rs + i + 3];
    float a0 = asrc[(size_t)s0 * 8 + h];
    float a1 = asrc[(size_t)s1 * 8 + h];
    float a2 = asrc[(size_t)s2 * 8 + h];
    float a3 = asrc[(size_t)s3 * 8 + h];
    float x0 = h1[(size_t)s0 * 64 + lane];
    float x1 = h1[(size_t)s1 * 64 + lane];
    float x2 = h1[(size_t)s2 * 64 + lane];
    float x3 = h1[(size_t)s3 * 64 + lane];
    float p0 = expf(lrelu(a0 + ad));
    float p1 = expf(lrelu(a1 + ad));
    float p2 = expf(lrelu(a2 + ad));
    float p3 = expf(lrelu(a3 + ad));
    acc += p0 * x0 + p1 * x1 + p2 * x2 + p3 * x3;
    zs += (p0 + p1) + (p2 + p3);
  }
  for (; i < n; ++i) {
    int s0 = csr[rs + i];
    float p0 = expf(lrelu(asrc[(size_t)s0 * 8 + h] + ad));
    acc += p0 * h1[(size_t)s0 * 64 + lane];
    zs += p0;
  }
  // self loop
  {
    float p = expf(lrelu(asrc[(size_t)d * 8 + h] + ad));
    acc += p * h1[(size_t)d * 64 + lane];
    zs += p;
  }
  act[(size_t)d * 64 + lane] = eluf(acc / (zs + 1e-16f) + b1[lane]);
}

// ---------------- layer2 node kernel: h2 = act @ W2, attention coefficients ----------------
__global__ __launch_bounds__(256) void node_l2(const float* __restrict__ act,
                                               const float* __restrict__ W2,
                                               const float* __restrict__ as2,
                                               const float* __restrict__ ad2,
                                               float* __restrict__ h2,
                                               float* __restrict__ asrc2,
                                               float* __restrict__ adst2, int N) {
  __shared__ float acts[64 * 68];
  __shared__ float w2[64 * 40];
  __shared__ float h2s[64 * 41];
  const int tid = threadIdx.x;
  const int n0 = blockIdx.x * 64;

  for (int q = tid; q < 64 * 40; q += 256) w2[q] = W2[q];

#pragma unroll
  for (int p = 0; p < 4; ++p) {
    int q = tid + p * 256;
    int r = q >> 4, c4 = q & 15;
    int n = n0 + r;
    if (n >= N) n = N - 1;
    float4 v = *(const float4*)&act[(size_t)n * 64 + c4 * 4];
    *(float4*)&acts[r * 68 + c4 * 4] = v;
  }
  __syncthreads();

  const int nl = tid >> 2;
  const int k0 = (tid & 3) * 10;
  float hv[10];
#pragma unroll
  for (int i = 0; i < 10; ++i) hv[i] = 0.0f;
  for (int j = 0; j < 64; ++j) {
    float a = acts[nl * 68 + j];
#pragma unroll
    for (int i = 0; i < 10; ++i) hv[i] += a * w2[j * 40 + k0 + i];
  }
  int n = n0 + nl;
  if (n < N) {
#pragma unroll
    for (int i = 0; i < 10; ++i) h2[(size_t)n * 40 + k0 + i] = hv[i];
  }
#pragma unroll
  for (int i = 0; i < 10; ++i) h2s[nl * 41 + k0 + i] = hv[i];
  __syncthreads();

  if (tid < 64) {
    int nn = n0 + tid;
    float s1 = 0.0f, s2 = 0.0f;
    for (int k = 0; k < 40; ++k) {
      float h = h2s[tid * 41 + k];
      s1 += h * as2[k];
      s2 += h * ad2[k];
    }
    if (nn < N) {
      asrc2[nn] = s1;
      adst2[nn] = s2;
    }
  }
}

// ---------------- layer 2 aggregation: wave per dst node ----------------
__global__ __launch_bounds__(256) void agg2(const int* __restrict__ rowstart,
                                            const int* __restrict__ deg,
                                            const int* __restrict__ csr,
                                            const float* __restrict__ asrc,
                                            const float* __restrict__ adst,
                                            const float* __restrict__ h2,
                                            const float* __restrict__ b2,
                                            float* __restrict__ out, int N) {
  int wid = (blockIdx.x * 256 + threadIdx.x) >> 6;
  if (wid >= N) return;
  int lane = threadIdx.x & 63;
  int d = wid;
  float ad = adst[d];
  int rs = rowstart[d], n = deg[d];
  float acc = 0.0f, zs = 0.0f;
  int i = 0;
  for (; i + 3 < n; i += 4) {
    int s0 = csr[rs + i];
    int s1 = csr[rs + i + 1];
    int s2 = csr[rs + i + 2];
    int s3 = csr[rs + i + 3];
    float a0 = asrc[s0];
    float a1 = asrc[s1];
    float a2 = asrc[s2];
    float a3 = asrc[s3];
    float x0 = lane < 40 ? h2[(size_t)s0 * 40 + lane] : 0.0f;
    float x1 = lane < 40 ? h2[(size_t)s1 * 40 + lane] : 0.0f;
    float x2 = lane < 40 ? h2[(size_t)s2 * 40 + lane] : 0.0f;
    float x3 = lane < 40 ? h2[(size_t)s3 * 40 + lane] : 0.0f;
    float p0 = expf(lrelu(a0 + ad));
    float p1 = expf(lrelu(a1 + ad));
    float p2 = expf(lrelu(a2 + ad));
    float p3 = expf(lrelu(a3 + ad));
    acc += p0 * x0 + p1 * x1 + p2 * x2 + p3 * x3;
    zs += (p0 + p1) + (p2 + p3);
  }
  for (; i < n; ++i) {
    int s0 = csr[rs + i];
    float p0 = expf(lrelu(asrc[s0] + ad));
    float x0 = lane < 40 ? h2[(size_t)s0 * 40 + lane] : 0.0f;
    acc += p0 * x0;
    zs += p0;
  }
  {
    float p = expf(lrelu(asrc[d] + ad));
    float x = lane < 40 ? h2[(size_t)d * 40 + lane] : 0.0f;
    acc += p * x;
    zs += p;
  }
  if (lane < 40) out[(size_t)d * 40 + lane] = acc / (zs + 1e-16f) + b2[lane];
}

extern "C" void kernel_launch(void* const* d_in, const int* in_sizes, int n_in,
                              void* d_out, int out_size, void* d_ws, size_t ws_size,
                              hipStream_t stream) {
  const float* x   = (const float*)d_in[0];
  const int*   ei  = (const int*)d_in[1];
  const float* W1  = (const float*)d_in[2];
  const float* as1 = (const float*)d_in[3];
  const float* ad1 = (const float*)d_in[4];
  const float* b1  = (const float*)d_in[5];
  const float* W2  = (const float*)d_in[6];
  const float* as2 = (const float*)d_in[7];
  const float* ad2 = (const float*)d_in[8];
  const float* b2  = (const float*)d_in[9];
  float* out = (float*)d_out;

  const int N = in_sizes[0] / 512;
  const int E = in_sizes[1] / 2;
  const int NB = (N + 255) / 256;

  float* ws = (float*)d_ws;
  size_t o = 0;
  float* h1    = ws + o; o += (size_t)N * 64;
  float* act   = ws + o; o += (size_t)N * 64;
  float* h2    = ws + o; o += (size_t)N * 40;
  float* asrc1 = ws + o; o += (size_t)N * 8;
  float* adst1 = ws + o; o += (size_t)N * 8;
  float* asrc2 = ws + o; o += (size_t)N;
  float* adst2 = ws + o; o += (size_t)N;
  int* deg      = (int*)(ws + o); o += (size_t)N;
  int* rowstart = (int*)(ws + o); o += (size_t)N;
  int* bsum     = (int*)(ws + o); o += (size_t)NB + 16;
  int* rankv    = (int*)(ws + o); o += (size_t)E;
  int* csr      = (int*)(ws + o); o += (size_t)E;

  hipMemsetAsync(deg, 0, (size_t)N * sizeof(int), stream);

  // K1: gemm1 blocks first (long-running), count blocks backfill
  const int NBg = (N + 127) / 128;
  const int NBc = (E + 1023) / 1024;
  k_gemm_count<<<NBg + NBc, 256, 0, stream>>>(x, W1, h1, ei, deg, rankv, N, E, NBg);

  scan1<<<NB, 256, 0, stream>>>(deg, bsum, N);
  scan2<<<1, 512, 0, stream>>>(bsum, NB);
  scan3<<<NB, 256, 0, stream>>>(deg, bsum, rowstart, N);

  // K2: scatter (atomic-free) + attention coefficients
  const int NBs = (E + 1023) / 1024;
  const int NBa = (N * 8 + 255) / 256;
  k_scatter_attn<<<NBs + NBa, 256, 0, stream>>>(ei, rankv, rowstart, csr, h1, as1, ad1,
                                                asrc1, adst1, N, E, NBs);

  agg1<<<(N * 64 + 255) / 256, 256, 0, stream>>>(rowstart, deg, csr, asrc1, adst1, h1, b1,
                                                 act, N);

  node_l2<<<(N + 63) / 64, 256, 0, stream>>>(act, W2, as2, ad2, h2, asrc2, adst2, N);

  agg2<<<(N * 64 + 255) / 256, 256, 0, stream>>>(rowstart, deg, csr, asrc2, adst2, h2, b2,
                                                 out, N);
}

// Round 5
// 562.468 us; speedup vs baseline: 5.2129x; 1.1011x over previous
//
#include <hip/hip_runtime.h>
#include <math.h>

#define NEG 0.2f
#define CBITS 7               // coarse bucket = dst >> 7 (128 nodes/bucket)
#define CNODES 128

__device__ __forceinline__ float lrelu(float v) { return v > 0.0f ? v : NEG * v; }
__device__ __forceinline__ float eluf(float x) { return x > 0.0f ? x : expf(x) - 1.0f; }

// ---------------- K1: gemm1 + fused attn-coef epilogue (blocks [0,NBg)) ----------------
//                     + coarse histogram (blocks [NBg, NBg+NBc))
__global__ __launch_bounds__(256) void k_gemm_coarse(const float* __restrict__ x,
                                                     const float* __restrict__ W,
                                                     float* __restrict__ h1,
                                                     const float* __restrict__ as1,
                                                     const float* __restrict__ ad1,
                                                     float* __restrict__ asrc1,
                                                     float* __restrict__ adst1,
                                                     const int* __restrict__ ei,
                                                     int* __restrict__ coarse_hist,
                                                     int N, int E, int NBg, int NBK) {
  __shared__ float xs[128 * 40];
  __shared__ float ws[32 * 68];
  const int tid = threadIdx.x;

  if ((int)blockIdx.x >= NBg) {
    // -------- coarse count branch: 16384 edges/block, LDS histogram --------
    int* lh = (int*)xs;
    for (int q = tid; q < NBK; q += 256) lh[q] = 0;
    __syncthreads();
    int e_base = ((int)blockIdx.x - NBg) * 16384;
#pragma unroll 4
    for (int u = 0; u < 16; ++u) {
      int e = e_base + u * 1024 + tid * 4;
      if (e + 3 < E) {
        int4 d4 = *(const int4*)&ei[E + e];
        atomicAdd(&lh[d4.x >> CBITS], 1);
        atomicAdd(&lh[d4.y >> CBITS], 1);
        atomicAdd(&lh[d4.z >> CBITS], 1);
        atomicAdd(&lh[d4.w >> CBITS], 1);
      } else {
        for (int v = 0; v < 4; ++v) {
          int ee = e + v;
          if (ee < E) atomicAdd(&lh[ei[E + ee] >> CBITS], 1);
        }
      }
    }
    __syncthreads();
    for (int q = tid; q < NBK; q += 256) {
      int c = lh[q];
      if (c > 0) atomicAdd(&coarse_hist[q], c);
    }
    return;
  }

  // -------- gemm branch --------
  const int n0 = blockIdx.x * 128;
  const int jg = tid & 15;
  const int ig = tid >> 4;
  const int j0 = jg * 4;

  float acc[8][4];
#pragma unroll
  for (int i = 0; i < 8; ++i)
#pragma unroll
    for (int c = 0; c < 4; ++c) acc[i][c] = 0.0f;

  for (int kc = 0; kc < 512; kc += 32) {
#pragma unroll
    for (int p = 0; p < 4; ++p) {
      int q = tid + p * 256;
      int r = q >> 3, c4 = q & 7;
      int n = n0 + r;
      if (n >= N) n = N - 1;
      float4 v = *(const float4*)&x[(size_t)n * 512 + kc + c4 * 4];
      *(float4*)&xs[r * 40 + c4 * 4] = v;
    }
#pragma unroll
    for (int p = 0; p < 2; ++p) {
      int q = tid + p * 256;
      int r = q >> 4, c4 = q & 15;
      float4 v = *(const float4*)&W[(size_t)(kc + r) * 64 + c4 * 4];
      *(float4*)&ws[r * 68 + c4 * 4] = v;
    }
    __syncthreads();

#pragma unroll
    for (int k = 0; k < 32; k += 4) {
      float4 wf[4];
#pragma unroll
      for (int kk = 0; kk < 4; ++kk) wf[kk] = *(const float4*)&ws[(k + kk) * 68 + j0];
#pragma unroll
      for (int i = 0; i < 8; ++i) {
        int r = ig + 16 * i;
        float4 xf = *(const float4*)&xs[r * 40 + k];
        float xv;
        xv = xf.x;
        acc[i][0] += xv * wf[0].x; acc[i][1] += xv * wf[0].y;
        acc[i][2] += xv * wf[0].z; acc[i][3] += xv * wf[0].w;
        xv = xf.y;
        acc[i][0] += xv * wf[1].x; acc[i][1] += xv * wf[1].y;
        acc[i][2] += xv * wf[1].z; acc[i][3] += xv * wf[1].w;
        xv = xf.z;
        acc[i][0] += xv * wf[2].x; acc[i][1] += xv * wf[2].y;
        acc[i][2] += xv * wf[2].z; acc[i][3] += xv * wf[2].w;
        xv = xf.w;
        acc[i][0] += xv * wf[3].x; acc[i][1] += xv * wf[3].y;
        acc[i][2] += xv * wf[3].z; acc[i][3] += xv * wf[3].w;
      }
    }
    __syncthreads();
  }

  // epilogue: h1 store + fused attention coefficients
  float as_c[4], ad_c[4];
#pragma unroll
  for (int c = 0; c < 4; ++c) {
    as_c[c] = as1[j0 + c];
    ad_c[c] = ad1[j0 + c];
  }
  const int h = jg >> 1;  // the head covered by this lane pair
#pragma unroll
  for (int i = 0; i < 8; ++i) {
    int n = n0 + ig + 16 * i;
    float ps = acc[i][0] * as_c[0] + acc[i][1] * as_c[1] + acc[i][2] * as_c[2] +
               acc[i][3] * as_c[3];
    float pd = acc[i][0] * ad_c[0] + acc[i][1] * ad_c[1] + acc[i][2] * ad_c[2] +
               acc[i][3] * ad_c[3];
    ps += __shfl_xor(ps, 1, 64);
    pd += __shfl_xor(pd, 1, 64);
    if (n < N) {
      *(float4*)&h1[(size_t)n * 64 + j0] =
          make_float4(acc[i][0], acc[i][1], acc[i][2], acc[i][3]);
      if ((jg & 1) == 0) {
        asrc1[(size_t)n * 8 + h] = ps;
        adst1[(size_t)n * 8 + h] = pd;
      }
    }
  }
}

// ---------------- K2: scan coarse histogram (single block, NBK <= 1024) ----------------
__global__ __launch_bounds__(1024) void k_coarse_scan(const int* __restrict__ coarse_hist,
                                                      int* __restrict__ coarse_off,
                                                      int* __restrict__ cursor,
                                                      int NBK, int E) {
  __shared__ int s[1024];
  int t = threadIdx.x;
  int own = t < NBK ? coarse_hist[t] : 0;
  s[t] = own;
  __syncthreads();
  for (int o = 1; o < 1024; o <<= 1) {
    int add = t >= o ? s[t - o] : 0;
    __syncthreads();
    s[t] += add;
    __syncthreads();
  }
  if (t < NBK) {
    int excl = s[t] - own;
    coarse_off[t] = excl;
    cursor[t] = excl;
  }
  if (t == 0) coarse_off[NBK] = E;
}

// ---------------- K3: bucket scatter (LDS-rank aggregated) ----------------
// writes bucketed[pos] = (src << CBITS) | (dst & (CNODES-1)), grouped by coarse bucket
__global__ __launch_bounds__(256) void k_bucket_scatter(const int* __restrict__ ei,
                                                        int* __restrict__ cursor,
                                                        int* __restrict__ bucketed,
                                                        int E, int NBK) {
  __shared__ int hist[1024];
  __shared__ int basev[1024];
  const int tid = threadIdx.x;
  for (int q = tid; q < NBK; q += 256) hist[q] = 0;
  __syncthreads();
  const int e0 = blockIdx.x * 4096;
  int b[16], r[16];
#pragma unroll
  for (int u = 0; u < 16; ++u) {
    int e = e0 + u * 256 + tid;
    if (e < E) {
      int d = ei[E + e];
      b[u] = d >> CBITS;
      r[u] = atomicAdd(&hist[b[u]], 1);
    } else {
      b[u] = -1;
    }
  }
  __syncthreads();
  for (int q = tid; q < NBK; q += 256) {
    int c = hist[q];
    basev[q] = c > 0 ? atomicAdd(&cursor[q], c) : 0;
  }
  __syncthreads();
#pragma unroll
  for (int u = 0; u < 16; ++u) {
    if (b[u] >= 0) {
      int e = e0 + u * 256 + tid;
      int srcv = ei[e];
      int d = ei[E + e];
      bucketed[basev[b[u]] + r[u]] = (srcv << CBITS) | (d & (CNODES - 1));
    }
  }
}

// ---------------- K4: per-bucket fine CSR build (block per coarse bucket) ----------------
__global__ __launch_bounds__(256) void k_fine_csr(const int* __restrict__ bucketed,
                                                  const int* __restrict__ coarse_off,
                                                  int* __restrict__ rowstart,
                                                  int* __restrict__ deg,
                                                  int* __restrict__ csr, int N) {
  __shared__ int h[CNODES];
  __shared__ int excl[CNODES];
  const int tid = threadIdx.x;
  const int bkt = blockIdx.x;
  const int base = coarse_off[bkt];
  const int cnt = coarse_off[bkt + 1] - base;

  if (tid < CNODES) h[tid] = 0;
  __syncthreads();
  for (int i = tid; i < cnt; i += 256) atomicAdd(&h[bucketed[base + i] & (CNODES - 1)], 1);
  __syncthreads();
  // scan 128 counters with one wave (2 elems per lane)
  if (tid < 64) {
    int a = h[2 * tid], c = h[2 * tid + 1];
    int ps = a + c;
    int sv = ps;
    for (int o = 1; o < 64; o <<= 1) {
      int tv = __shfl_up(sv, o, 64);
      if (tid >= o) sv += tv;
    }
    int e0v = sv - ps;
    excl[2 * tid] = e0v;
    excl[2 * tid + 1] = e0v + a;
  }
  __syncthreads();
  if (tid < CNODES) {
    int node = bkt * CNODES + tid;
    if (node < N) {
      rowstart[node] = base + excl[tid];
      deg[node] = h[tid];
    }
  }
  __syncthreads();
  if (tid < CNODES) h[tid] = 0;
  __syncthreads();
  for (int i = tid; i < cnt; i += 256) {
    int v = bucketed[base + i];
    int loc = v & (CNODES - 1);
    int r = atomicAdd(&h[loc], 1);
    csr[base + excl[loc] + r] = v >> CBITS;
  }
}

// ---------------- layer 1 aggregation: wave per dst node, fused softmax+bias+ELU ---------
__global__ __launch_bounds__(256) void agg1(const int* __restrict__ rowstart,
                                            const int* __restrict__ deg,
                                            const int* __restrict__ csr,
                                            const float* __restrict__ asrc,
                                            const float* __restrict__ adst,
                                            const float* __restrict__ h1,
                                            const float* __restrict__ b1,
                                            float* __restrict__ act, int N) {
  int wid = (blockIdx.x * 256 + threadIdx.x) >> 6;
  if (wid >= N) return;
  int lane = threadIdx.x & 63;
  int h = lane >> 3;
  int d = wid;
  float ad = adst[(size_t)d * 8 + h];
  int rs = rowstart[d], n = deg[d];
  float acc = 0.0f, zs = 0.0f;
  int i = 0;
  for (; i + 3 < n; i += 4) {
    int s0 = csr[rs + i];
    int s1 = csr[rs + i + 1];
    int s2 = csr[rs + i + 2];
    int s3 = csr[rs + i + 3];
    float a0 = asrc[(size_t)s0 * 8 + h];
    float a1 = asrc[(size_t)s1 * 8 + h];
    float a2 = asrc[(size_t)s2 * 8 + h];
    float a3 = asrc[(size_t)s3 * 8 + h];
    float x0 = h1[(size_t)s0 * 64 + lane];
    float x1 = h1[(size_t)s1 * 64 + lane];
    float x2 = h1[(size_t)s2 * 64 + lane];
    float x3 = h1[(size_t)s3 * 64 + lane];
    float p0 = expf(lrelu(a0 + ad));
    float p1 = expf(lrelu(a1 + ad));
    float p2 = expf(lrelu(a2 + ad));
    float p3 = expf(lrelu(a3 + ad));
    acc += p0 * x0 + p1 * x1 + p2 * x2 + p3 * x3;
    zs += (p0 + p1) + (p2 + p3);
  }
  for (; i < n; ++i) {
    int s0 = csr[rs + i];
    float p0 = expf(lrelu(asrc[(size_t)s0 * 8 + h] + ad));
    acc += p0 * h1[(size_t)s0 * 64 + lane];
    zs += p0;
  }
  {
    float p = expf(lrelu(asrc[(size_t)d * 8 + h] + ad));
    acc += p * h1[(size_t)d * 64 + lane];
    zs += p;
  }
  act[(size_t)d * 64 + lane] = eluf(acc / (zs + 1e-16f) + b1[lane]);
}

// ---------------- layer2 node kernel: h2 = act @ W2, attention coefficients ----------------
__global__ __launch_bounds__(256) void node_l2(const float* __restrict__ act,
                                               const float* __restrict__ W2,
                                               const float* __restrict__ as2,
                                               const float* __restrict__ ad2,
                                               float* __restrict__ h2,
                                               float* __restrict__ asrc2,
                                               float* __restrict__ adst2, int N) {
  __shared__ float acts[64 * 68];
  __shared__ float w2[64 * 40];
  __shared__ float h2s[64 * 41];
  const int tid = threadIdx.x;
  const int n0 = blockIdx.x * 64;

  for (int q = tid; q < 64 * 40; q += 256) w2[q] = W2[q];

#pragma unroll
  for (int p = 0; p < 4; ++p) {
    int q = tid + p * 256;
    int r = q >> 4, c4 = q & 15;
    int n = n0 + r;
    if (n >= N) n = N - 1;
    float4 v = *(const float4*)&act[(size_t)n * 64 + c4 * 4];
    *(float4*)&acts[r * 68 + c4 * 4] = v;
  }
  __syncthreads();

  const int nl = tid >> 2;
  const int k0 = (tid & 3) * 10;
  float hv[10];
#pragma unroll
  for (int i = 0; i < 10; ++i) hv[i] = 0.0f;
  for (int j = 0; j < 64; ++j) {
    float a = acts[nl * 68 + j];
#pragma unroll
    for (int i = 0; i < 10; ++i) hv[i] += a * w2[j * 40 + k0 + i];
  }
  int n = n0 + nl;
  if (n < N) {
#pragma unroll
    for (int i = 0; i < 10; ++i) h2[(size_t)n * 40 + k0 + i] = hv[i];
  }
#pragma unroll
  for (int i = 0; i < 10; ++i) h2s[nl * 41 + k0 + i] = hv[i];
  __syncthreads();

  if (tid < 64) {
    int nn = n0 + tid;
    float s1 = 0.0f, s2 = 0.0f;
    for (int k = 0; k < 40; ++k) {
      float h = h2s[tid * 41 + k];
      s1 += h * as2[k];
      s2 += h * ad2[k];
    }
    if (nn < N) {
      asrc2[nn] = s1;
      adst2[nn] = s2;
    }
  }
}

// ---------------- layer 2 aggregation: wave per dst node ----------------
__global__ __launch_bounds__(256) void agg2(const int* __restrict__ rowstart,
                                            const int* __restrict__ deg,
                                            const int* __restrict__ csr,
                                            const float* __restrict__ asrc,
                                            const float* __restrict__ adst,
                                            const float* __restrict__ h2,
                                            const float* __restrict__ b2,
                                            float* __restrict__ out, int N) {
  int wid = (blockIdx.x * 256 + threadIdx.x) >> 6;
  if (wid >= N) return;
  int lane = threadIdx.x & 63;
  int d = wid;
  float ad = adst[d];
  int rs = rowstart[d], n = deg[d];
  float acc = 0.0f, zs = 0.0f;
  int i = 0;
  for (; i + 3 < n; i += 4) {
    int s0 = csr[rs + i];
    int s1 = csr[rs + i + 1];
    int s2 = csr[rs + i + 2];
    int s3 = csr[rs + i + 3];
    float a0 = asrc[s0];
    float a1 = asrc[s1];
    float a2 = asrc[s2];
    float a3 = asrc[s3];
    float x0 = lane < 40 ? h2[(size_t)s0 * 40 + lane] : 0.0f;
    float x1 = lane < 40 ? h2[(size_t)s1 * 40 + lane] : 0.0f;
    float x2 = lane < 40 ? h2[(size_t)s2 * 40 + lane] : 0.0f;
    float x3 = lane < 40 ? h2[(size_t)s3 * 40 + lane] : 0.0f;
    float p0 = expf(lrelu(a0 + ad));
    float p1 = expf(lrelu(a1 + ad));
    float p2 = expf(lrelu(a2 + ad));
    float p3 = expf(lrelu(a3 + ad));
    acc += p0 * x0 + p1 * x1 + p2 * x2 + p3 * x3;
    zs += (p0 + p1) + (p2 + p3);
  }
  for (; i < n; ++i) {
    int s0 = csr[rs + i];
    float p0 = expf(lrelu(asrc[s0] + ad));
    float x0 = lane < 40 ? h2[(size_t)s0 * 40 + lane] : 0.0f;
    acc += p0 * x0;
    zs += p0;
  }
  {
    float p = expf(lrelu(asrc[d] + ad));
    float x = lane < 40 ? h2[(size_t)d * 40 + lane] : 0.0f;
    acc += p * x;
    zs += p;
  }
  if (lane < 40) out[(size_t)d * 40 + lane] = acc / (zs + 1e-16f) + b2[lane];
}

extern "C" void kernel_launch(void* const* d_in, const int* in_sizes, int n_in,
                              void* d_out, int out_size, void* d_ws, size_t ws_size,
                              hipStream_t stream) {
  const float* x   = (const float*)d_in[0];
  const int*   ei  = (const int*)d_in[1];
  const float* W1  = (const float*)d_in[2];
  const float* as1 = (const float*)d_in[3];
  const float* ad1 = (const float*)d_in[4];
  const float* b1  = (const float*)d_in[5];
  const float* W2  = (const float*)d_in[6];
  const float* as2 = (const float*)d_in[7];
  const float* ad2 = (const float*)d_in[8];
  const float* b2  = (const float*)d_in[9];
  float* out = (float*)d_out;

  const int N = in_sizes[0] / 512;
  const int E = in_sizes[1] / 2;
  const int NBK = (N + CNODES - 1) / CNODES;  // coarse buckets (must be <= 1024)

  float* ws = (float*)d_ws;
  size_t o = 0;
  float* h1    = ws + o; o += (size_t)N * 64;
  float* act   = ws + o; o += (size_t)N * 64;
  float* h2    = ws + o; o += (size_t)N * 40;
  float* asrc1 = ws + o; o += (size_t)N * 8;
  float* adst1 = ws + o; o += (size_t)N * 8;
  float* asrc2 = ws + o; o += (size_t)N;
  float* adst2 = ws + o; o += (size_t)N;
  int* deg         = (int*)(ws + o); o += (size_t)N;
  int* rowstart    = (int*)(ws + o); o += (size_t)N;
  int* coarse_hist = (int*)(ws + o); o += 1024;
  int* coarse_off  = (int*)(ws + o); o += 1056;
  int* cursor      = (int*)(ws + o); o += 1024;
  int* bucketed    = (int*)(ws + o); o += (size_t)E;
  int* csr         = (int*)(ws + o); o += (size_t)E;

  hipMemsetAsync(coarse_hist, 0, 1024 * sizeof(int), stream);

  // K1: gemm (+fused attn coefficients) blocks first, coarse-count blocks backfill
  const int NBg = (N + 127) / 128;
  const int NBc = (E + 16383) / 16384;
  k_gemm_coarse<<<NBg + NBc, 256, 0, stream>>>(x, W1, h1, as1, ad1, asrc1, adst1, ei,
                                               coarse_hist, N, E, NBg, NBK);

  // K2: scan coarse histogram
  k_coarse_scan<<<1, 1024, 0, stream>>>(coarse_hist, coarse_off, cursor, NBK, E);

  // K3: bucket scatter
  const int NB3 = (E + 4095) / 4096;
  k_bucket_scatter<<<NB3, 256, 0, stream>>>(ei, cursor, bucketed, E, NBK);

  // K4: per-bucket fine CSR
  k_fine_csr<<<NBK, 256, 0, stream>>>(bucketed, coarse_off, rowstart, deg, csr, N);

  // layer 1 aggregation (fused softmax-denominator, bias, ELU)
  agg1<<<(N * 64 + 255) / 256, 256, 0, stream>>>(rowstart, deg, csr, asrc1, adst1, h1, b1,
                                                 act, N);

  // layer 2 dense part
  node_l2<<<(N + 63) / 64, 256, 0, stream>>>(act, W2, as2, ad2, h2, asrc2, adst2, N);

  // layer 2 aggregation
  agg2<<<(N * 64 + 255) / 256, 256, 0, stream>>>(rowstart, deg, csr, asrc2, adst2, h2, b2,
                                                 out, N);
}

// Round 6
// 531.859 us; speedup vs baseline: 5.5129x; 1.0576x over previous
//
#include <hip/hip_runtime.h>
#include <math.h>

#define NEG 0.2f
#define CBITS 7               // coarse bucket = dst >> 7 (128 nodes/bucket)
#define CNODES 128

// leaky-relu + exp via hardware exp: lrelu(v) = max(v, 0.2v); __expf -> v_exp_f32
__device__ __forceinline__ float pexp(float v) { return __expf(fmaxf(v, NEG * v)); }
__device__ __forceinline__ float eluf(float x) { return x > 0.0f ? x : __expf(x) - 1.0f; }

// ---------------- K1: gemm1 + fused attn-coef epilogue (blocks [0,NBg)) ----------------
//                     + coarse histogram (blocks [NBg, NBg+NBc))
__global__ __launch_bounds__(256) void k_gemm_coarse(const float* __restrict__ x,
                                                     const float* __restrict__ W,
                                                     float* __restrict__ h1,
                                                     const float* __restrict__ as1,
                                                     const float* __restrict__ ad1,
                                                     float* __restrict__ asrc1,
                                                     float* __restrict__ adst1,
                                                     const int* __restrict__ ei,
                                                     int* __restrict__ coarse_hist,
                                                     int N, int E, int NBg, int NBK) {
  __shared__ float xs[128 * 40];
  __shared__ float ws[32 * 68];
  const int tid = threadIdx.x;

  if ((int)blockIdx.x >= NBg) {
    // -------- coarse count branch: 16384 edges/block, LDS histogram --------
    int* lh = (int*)xs;
    for (int q = tid; q < NBK; q += 256) lh[q] = 0;
    __syncthreads();
    int e_base = ((int)blockIdx.x - NBg) * 16384;
#pragma unroll 4
    for (int u = 0; u < 16; ++u) {
      int e = e_base + u * 1024 + tid * 4;
      if (e + 3 < E) {
        int4 d4 = *(const int4*)&ei[E + e];
        atomicAdd(&lh[d4.x >> CBITS], 1);
        atomicAdd(&lh[d4.y >> CBITS], 1);
        atomicAdd(&lh[d4.z >> CBITS], 1);
        atomicAdd(&lh[d4.w >> CBITS], 1);
      } else {
        for (int v = 0; v < 4; ++v) {
          int ee = e + v;
          if (ee < E) atomicAdd(&lh[ei[E + ee] >> CBITS], 1);
        }
      }
    }
    __syncthreads();
    for (int q = tid; q < NBK; q += 256) {
      int c = lh[q];
      if (c > 0) atomicAdd(&coarse_hist[q], c);
    }
    return;
  }

  // -------- gemm branch --------
  const int n0 = blockIdx.x * 128;
  const int jg = tid & 15;
  const int ig = tid >> 4;
  const int j0 = jg * 4;

  float acc[8][4];
#pragma unroll
  for (int i = 0; i < 8; ++i)
#pragma unroll
    for (int c = 0; c < 4; ++c) acc[i][c] = 0.0f;

  for (int kc = 0; kc < 512; kc += 32) {
#pragma unroll
    for (int p = 0; p < 4; ++p) {
      int q = tid + p * 256;
      int r = q >> 3, c4 = q & 7;
      int n = n0 + r;
      if (n >= N) n = N - 1;
      float4 v = *(const float4*)&x[(size_t)n * 512 + kc + c4 * 4];
      *(float4*)&xs[r * 40 + c4 * 4] = v;
    }
#pragma unroll
    for (int p = 0; p < 2; ++p) {
      int q = tid + p * 256;
      int r = q >> 4, c4 = q & 15;
      float4 v = *(const float4*)&W[(size_t)(kc + r) * 64 + c4 * 4];
      *(float4*)&ws[r * 68 + c4 * 4] = v;
    }
    __syncthreads();

#pragma unroll
    for (int k = 0; k < 32; k += 4) {
      float4 wf[4];
#pragma unroll
      for (int kk = 0; kk < 4; ++kk) wf[kk] = *(const float4*)&ws[(k + kk) * 68 + j0];
#pragma unroll
      for (int i = 0; i < 8; ++i) {
        int r = ig + 16 * i;
        float4 xf = *(const float4*)&xs[r * 40 + k];
        float xv;
        xv = xf.x;
        acc[i][0] += xv * wf[0].x; acc[i][1] += xv * wf[0].y;
        acc[i][2] += xv * wf[0].z; acc[i][3] += xv * wf[0].w;
        xv = xf.y;
        acc[i][0] += xv * wf[1].x; acc[i][1] += xv * wf[1].y;
        acc[i][2] += xv * wf[1].z; acc[i][3] += xv * wf[1].w;
        xv = xf.z;
        acc[i][0] += xv * wf[2].x; acc[i][1] += xv * wf[2].y;
        acc[i][2] += xv * wf[2].z; acc[i][3] += xv * wf[2].w;
        xv = xf.w;
        acc[i][0] += xv * wf[3].x; acc[i][1] += xv * wf[3].y;
        acc[i][2] += xv * wf[3].z; acc[i][3] += xv * wf[3].w;
      }
    }
    __syncthreads();
  }

  // epilogue: h1 store + fused attention coefficients
  float as_c[4], ad_c[4];
#pragma unroll
  for (int c = 0; c < 4; ++c) {
    as_c[c] = as1[j0 + c];
    ad_c[c] = ad1[j0 + c];
  }
  const int h = jg >> 1;  // the head covered by this lane pair
#pragma unroll
  for (int i = 0; i < 8; ++i) {
    int n = n0 + ig + 16 * i;
    float ps = acc[i][0] * as_c[0] + acc[i][1] * as_c[1] + acc[i][2] * as_c[2] +
               acc[i][3] * as_c[3];
    float pd = acc[i][0] * ad_c[0] + acc[i][1] * ad_c[1] + acc[i][2] * ad_c[2] +
               acc[i][3] * ad_c[3];
    ps += __shfl_xor(ps, 1, 64);
    pd += __shfl_xor(pd, 1, 64);
    if (n < N) {
      *(float4*)&h1[(size_t)n * 64 + j0] =
          make_float4(acc[i][0], acc[i][1], acc[i][2], acc[i][3]);
      if ((jg & 1) == 0) {
        asrc1[(size_t)n * 8 + h] = ps;
        adst1[(size_t)n * 8 + h] = pd;
      }
    }
  }
}

// ---------------- K2: scan coarse histogram (single block, NBK <= 1024) ----------------
__global__ __launch_bounds__(1024) void k_coarse_scan(const int* __restrict__ coarse_hist,
                                                      int* __restrict__ coarse_off,
                                                      int* __restrict__ cursor,
                                                      int NBK, int E) {
  __shared__ int s[1024];
  int t = threadIdx.x;
  int own = t < NBK ? coarse_hist[t] : 0;
  s[t] = own;
  __syncthreads();
  for (int o = 1; o < 1024; o <<= 1) {
    int add = t >= o ? s[t - o] : 0;
    __syncthreads();
    s[t] += add;
    __syncthreads();
  }
  if (t < NBK) {
    int excl = s[t] - own;
    coarse_off[t] = excl;
    cursor[t] = excl;
  }
  if (t == 0) coarse_off[NBK] = E;
}

// ---------------- K3: bucket scatter (LDS-rank aggregated) ----------------
__global__ __launch_bounds__(256) void k_bucket_scatter(const int* __restrict__ ei,
                                                        int* __restrict__ cursor,
                                                        int* __restrict__ bucketed,
                                                        int E, int NBK) {
  __shared__ int hist[1024];
  __shared__ int basev[1024];
  const int tid = threadIdx.x;
  for (int q = tid; q < NBK; q += 256) hist[q] = 0;
  __syncthreads();
  const int e0 = blockIdx.x * 4096;
  int b[16], r[16];
#pragma unroll
  for (int u = 0; u < 16; ++u) {
    int e = e0 + u * 256 + tid;
    if (e < E) {
      int d = ei[E + e];
      b[u] = d >> CBITS;
      r[u] = atomicAdd(&hist[b[u]], 1);
    } else {
      b[u] = -1;
    }
  }
  __syncthreads();
  for (int q = tid; q < NBK; q += 256) {
    int c = hist[q];
    basev[q] = c > 0 ? atomicAdd(&cursor[q], c) : 0;
  }
  __syncthreads();
#pragma unroll
  for (int u = 0; u < 16; ++u) {
    if (b[u] >= 0) {
      int e = e0 + u * 256 + tid;
      int srcv = ei[e];
      int d = ei[E + e];
      bucketed[basev[b[u]] + r[u]] = (srcv << CBITS) | (d & (CNODES - 1));
    }
  }
}

// ---------------- K4: per-bucket fine CSR build (block per coarse bucket) ----------------
__global__ __launch_bounds__(256) void k_fine_csr(const int* __restrict__ bucketed,
                                                  const int* __restrict__ coarse_off,
                                                  int* __restrict__ rowstart,
                                                  int* __restrict__ deg,
                                                  int* __restrict__ csr, int N) {
  __shared__ int h[CNODES];
  __shared__ int excl[CNODES];
  const int tid = threadIdx.x;
  const int bkt = blockIdx.x;
  const int base = coarse_off[bkt];
  const int cnt = coarse_off[bkt + 1] - base;

  if (tid < CNODES) h[tid] = 0;
  __syncthreads();
  for (int i = tid; i < cnt; i += 256) atomicAdd(&h[bucketed[base + i] & (CNODES - 1)], 1);
  __syncthreads();
  if (tid < 64) {
    int a = h[2 * tid], c = h[2 * tid + 1];
    int ps = a + c;
    int sv = ps;
    for (int o = 1; o < 64; o <<= 1) {
      int tv = __shfl_up(sv, o, 64);
      if (tid >= o) sv += tv;
    }
    int e0v = sv - ps;
    excl[2 * tid] = e0v;
    excl[2 * tid + 1] = e0v + a;
  }
  __syncthreads();
  if (tid < CNODES) {
    int node = bkt * CNODES + tid;
    if (node < N) {
      rowstart[node] = base + excl[tid];
      deg[node] = h[tid];
    }
  }
  __syncthreads();
  if (tid < CNODES) h[tid] = 0;
  __syncthreads();
  for (int i = tid; i < cnt; i += 256) {
    int v = bucketed[base + i];
    int loc = v & (CNODES - 1);
    int r = atomicAdd(&h[loc], 1);
    csr[base + excl[loc] + r] = v >> CBITS;
  }
}

// ---------------- layer 1 aggregation: wave per dst node, fused softmax+bias+ELU ---------
__global__ __launch_bounds__(256) void agg1(const int* __restrict__ rowstart,
                                            const int* __restrict__ deg,
                                            const int* __restrict__ csr,
                                            const float* __restrict__ asrc,
                                            const float* __restrict__ adst,
                                            const float* __restrict__ h1,
                                            const float* __restrict__ b1,
                                            float* __restrict__ act, int N) {
  int wid = (blockIdx.x * 256 + threadIdx.x) >> 6;
  if (wid >= N) return;
  int lane = threadIdx.x & 63;
  int h = lane >> 3;
  int d = wid;
  float ad = adst[(size_t)d * 8 + h];
  int rs = rowstart[d], n = deg[d];
  float acc = 0.0f, zs = 0.0f;
  int i = 0;
  for (; i + 3 < n; i += 4) {
    int s0 = csr[rs + i];
    int s1 = csr[rs + i + 1];
    int s2 = csr[rs + i + 2];
    int s3 = csr[rs + i + 3];
    float a0 = asrc[(size_t)s0 * 8 + h];
    float a1 = asrc[(size_t)s1 * 8 + h];
    float a2 = asrc[(size_t)s2 * 8 + h];
    float a3 = asrc[(size_t)s3 * 8 + h];
    float x0 = h1[(size_t)s0 * 64 + lane];
    float x1 = h1[(size_t)s1 * 64 + lane];
    float x2 = h1[(size_t)s2 * 64 + lane];
    float x3 = h1[(size_t)s3 * 64 + lane];
    float p0 = pexp(a0 + ad);
    float p1 = pexp(a1 + ad);
    float p2 = pexp(a2 + ad);
    float p3 = pexp(a3 + ad);
    acc += p0 * x0 + p1 * x1 + p2 * x2 + p3 * x3;
    zs += (p0 + p1) + (p2 + p3);
  }
  for (; i < n; ++i) {
    int s0 = csr[rs + i];
    float p0 = pexp(asrc[(size_t)s0 * 8 + h] + ad);
    acc += p0 * h1[(size_t)s0 * 64 + lane];
    zs += p0;
  }
  {
    float p = pexp(asrc[(size_t)d * 8 + h] + ad);
    acc += p * h1[(size_t)d * 64 + lane];
    zs += p;
  }
  act[(size_t)d * 64 + lane] = eluf(acc / (zs + 1e-16f) + b1[lane]);
}

// ---------------- layer2 node kernel: h2 = act @ W2, attention coefficients ----------------
__global__ __launch_bounds__(256) void node_l2(const float* __restrict__ act,
                                               const float* __restrict__ W2,
                                               const float* __restrict__ as2,
                                               const float* __restrict__ ad2,
                                               float* __restrict__ h2,
                                               float* __restrict__ asrc2,
                                               float* __restrict__ adst2, int N) {
  __shared__ float acts[64 * 68];
  __shared__ float w2[64 * 40];
  __shared__ float h2s[64 * 41];
  const int tid = threadIdx.x;
  const int n0 = blockIdx.x * 64;

  for (int q = tid; q < 64 * 40; q += 256) w2[q] = W2[q];

#pragma unroll
  for (int p = 0; p < 4; ++p) {
    int q = tid + p * 256;
    int r = q >> 4, c4 = q & 15;
    int n = n0 + r;
    if (n >= N) n = N - 1;
    float4 v = *(const float4*)&act[(size_t)n * 64 + c4 * 4];
    *(float4*)&acts[r * 68 + c4 * 4] = v;
  }
  __syncthreads();

  const int nl = tid >> 2;
  const int k0 = (tid & 3) * 10;
  float hv[10];
#pragma unroll
  for (int i = 0; i < 10; ++i) hv[i] = 0.0f;
  for (int j = 0; j < 64; ++j) {
    float a = acts[nl * 68 + j];
#pragma unroll
    for (int i = 0; i < 10; ++i) hv[i] += a * w2[j * 40 + k0 + i];
  }
  int n = n0 + nl;
  if (n < N) {
#pragma unroll
    for (int i = 0; i < 10; ++i) h2[(size_t)n * 40 + k0 + i] = hv[i];
  }
#pragma unroll
  for (int i = 0; i < 10; ++i) h2s[nl * 41 + k0 + i] = hv[i];
  __syncthreads();

  if (tid < 64) {
    int nn = n0 + tid;
    float s1 = 0.0f, s2 = 0.0f;
    for (int k = 0; k < 40; ++k) {
      float h = h2s[tid * 41 + k];
      s1 += h * as2[k];
      s2 += h * ad2[k];
    }
    if (nn < N) {
      asrc2[nn] = s1;
      adst2[nn] = s2;
    }
  }
}

// ---------------- layer 2 aggregation: wave per dst node ----------------
__global__ __launch_bounds__(256) void agg2(const int* __restrict__ rowstart,
                                            const int* __restrict__ deg,
                                            const int* __restrict__ csr,
                                            const float* __restrict__ asrc,
                                            const float* __restrict__ adst,
                                            const float* __restrict__ h2,
                                            const float* __restrict__ b2,
                                            float* __restrict__ out, int N) {
  int wid = (blockIdx.x * 256 + threadIdx.x) >> 6;
  if (wid >= N) return;
  int lane = threadIdx.x & 63;
  int d = wid;
  float ad = adst[d];
  int rs = rowstart[d], n = deg[d];
  float acc = 0.0f, zs = 0.0f;
  int i = 0;
  for (; i + 3 < n; i += 4) {
    int s0 = csr[rs + i];
    int s1 = csr[rs + i + 1];
    int s2 = csr[rs + i + 2];
    int s3 = csr[rs + i + 3];
    float a0 = asrc[s0];
    float a1 = asrc[s1];
    float a2 = asrc[s2];
    float a3 = asrc[s3];
    float x0 = lane < 40 ? h2[(size_t)s0 * 40 + lane] : 0.0f;
    float x1 = lane < 40 ? h2[(size_t)s1 * 40 + lane] : 0.0f;
    float x2 = lane < 40 ? h2[(size_t)s2 * 40 + lane] : 0.0f;
    float x3 = lane < 40 ? h2[(size_t)s3 * 40 + lane] : 0.0f;
    float p0 = pexp(a0 + ad);
    float p1 = pexp(a1 + ad);
    float p2 = pexp(a2 + ad);
    float p3 = pexp(a3 + ad);
    acc += p0 * x0 + p1 * x1 + p2 * x2 + p3 * x3;
    zs += (p0 + p1) + (p2 + p3);
  }
  for (; i < n; ++i) {
    int s0 = csr[rs + i];
    float p0 = pexp(asrc[s0] + ad);
    float x0 = lane < 40 ? h2[(size_t)s0 * 40 + lane] : 0.0f;
    acc += p0 * x0;
    zs += p0;
  }
  {
    float p = pexp(asrc[d] + ad);
    float x = lane < 40 ? h2[(size_t)d * 40 + lane] : 0.0f;
    acc += p * x;
    zs += p;
  }
  if (lane < 40) out[(size_t)d * 40 + lane] = acc / (zs + 1e-16f) + b2[lane];
}

extern "C" void kernel_launch(void* const* d_in, const int* in_sizes, int n_in,
                              void* d_out, int out_size, void* d_ws, size_t ws_size,
                              hipStream_t stream) {
  const float* x   = (const float*)d_in[0];
  const int*   ei  = (const int*)d_in[1];
  const float* W1  = (const float*)d_in[2];
  const float* as1 = (const float*)d_in[3];
  const float* ad1 = (const float*)d_in[4];
  const float* b1  = (const float*)d_in[5];
  const float* W2  = (const float*)d_in[6];
  const float* as2 = (const float*)d_in[7];
  const float* ad2 = (const float*)d_in[8];
  const float* b2  = (const float*)d_in[9];
  float* out = (float*)d_out;

  const int N = in_sizes[0] / 512;
  const int E = in_sizes[1] / 2;
  const int NBK = (N + CNODES - 1) / CNODES;

  float* ws = (float*)d_ws;
  size_t o = 0;
  float* h1    = ws + o; o += (size_t)N * 64;
  float* act   = ws + o; o += (size_t)N * 64;
  float* h2    = ws + o; o += (size_t)N * 40;
  float* asrc1 = ws + o; o += (size_t)N * 8;
  float* adst1 = ws + o; o += (size_t)N * 8;
  float* asrc2 = ws + o; o += (size_t)N;
  float* adst2 = ws + o; o += (size_t)N;
  int* deg         = (int*)(ws + o); o += (size_t)N;
  int* rowstart    = (int*)(ws + o); o += (size_t)N;
  int* coarse_hist = (int*)(ws + o); o += 1024;
  int* coarse_off  = (int*)(ws + o); o += 1056;
  int* cursor      = (int*)(ws + o); o += 1024;
  int* bucketed    = (int*)(ws + o); o += (size_t)E;
  int* csr         = (int*)(ws + o); o += (size_t)E;

  hipMemsetAsync(coarse_hist, 0, 1024 * sizeof(int), stream);

  const int NBg = (N + 127) / 128;
  const int NBc = (E + 16383) / 16384;
  k_gemm_coarse<<<NBg + NBc, 256, 0, stream>>>(x, W1, h1, as1, ad1, asrc1, adst1, ei,
                                               coarse_hist, N, E, NBg, NBK);

  k_coarse_scan<<<1, 1024, 0, stream>>>(coarse_hist, coarse_off, cursor, NBK, E);

  const int NB3 = (E + 4095) / 4096;
  k_bucket_scatter<<<NB3, 256, 0, stream>>>(ei, cursor, bucketed, E, NBK);

  k_fine_csr<<<NBK, 256, 0, stream>>>(bucketed, coarse_off, rowstart, deg, csr, N);

  agg1<<<(N * 64 + 255) / 256, 256, 0, stream>>>(rowstart, deg, csr, asrc1, adst1, h1, b1,
                                                 act, N);

  node_l2<<<(N + 63) / 64, 256, 0, stream>>>(act, W2, as2, ad2, h2, asrc2, adst2, N);

  agg2<<<(N * 64 + 255) / 256, 256, 0, stream>>>(rowstart, deg, csr, asrc2, adst2, h2, b2,
                                                 out, N);
}